// Round 1
// baseline (235.540 us; speedup 1.0000x reference)
//
#include <hip/hip_runtime.h>
#include <stdint.h>

#define C_DIM 512
#define H_HEADS 8
#define D_HEAD 64
#define B_BATCH 4
#define L_SEQ 2048
#define GROUPS 32
#define EPS_GN 1e-5f

typedef unsigned short u16;
typedef __attribute__((ext_vector_type(8))) __bf16 bf16x8;
typedef __attribute__((ext_vector_type(4))) float f32x4;

__device__ __forceinline__ u16 f2bf(float f) {
  unsigned u = __builtin_bit_cast(unsigned, f);
  unsigned r = u + 0x7FFFu + ((u >> 16) & 1u);
  return (u16)(r >> 16);
}

// ---------------------------------------------------------------- weights cvt
__global__ __launch_bounds__(256) void cvt_weights(const float* __restrict__ wq,
                                                   const float* __restrict__ wp,
                                                   u16* __restrict__ wq_bf,
                                                   u16* __restrict__ wp_bf) {
  int i = blockIdx.x * 256 + threadIdx.x;
  const int nq = 3 * C_DIM * C_DIM;      // 786432
  int idx = i * 4;
  const float* src;
  u16* dst;
  if (idx < nq) { src = wq + idx; dst = wq_bf + idx; }
  else          { src = wp + (idx - nq); dst = wp_bf + (idx - nq); }
  float4 v = *(const float4*)src;
  uint2 pk;
  pk.x = (unsigned)f2bf(v.x) | ((unsigned)f2bf(v.y) << 16);
  pk.y = (unsigned)f2bf(v.z) | ((unsigned)f2bf(v.w) << 16);
  *(uint2*)dst = pk;
}

// ---------------------------------------------------------------- group norm
// One block per (b, g). Writes h_t[b][l][c] bf16 (c contiguous).
__global__ __launch_bounds__(256) void groupnorm_kernel(const float* __restrict__ x,
                                                        const float* __restrict__ gamma,
                                                        const float* __restrict__ beta,
                                                        u16* __restrict__ h_t) {
  int bg = blockIdx.x;
  int b = bg >> 5, g = bg & 31;
  const float* base = x + ((size_t)(b * C_DIM + g * 16)) * L_SEQ;
  int t = threadIdx.x;
  int w = t >> 6;
  float s = 0.f, sq = 0.f;
  for (int i = 0; i < 32; ++i) {
    float4 v = ((const float4*)base)[t + i * 256];
    s += v.x + v.y + v.z + v.w;
    sq += v.x * v.x + v.y * v.y + v.z * v.z + v.w * v.w;
  }
  for (int off = 32; off; off >>= 1) { s += __shfl_down(s, off); sq += __shfl_down(sq, off); }
  __shared__ float red[8];
  if ((t & 63) == 0) { red[w * 2] = s; red[w * 2 + 1] = sq; }
  __syncthreads();
  float ts = red[0] + red[2] + red[4] + red[6];
  float tq = red[1] + red[3] + red[5] + red[7];
  float mean = ts * (1.f / 32768.f);
  float var = tq * (1.f / 32768.f) - mean * mean;
  float rstd = rsqrtf(var + EPS_GN);
  float ga[16], be[16];
#pragma unroll
  for (int c = 0; c < 16; ++c) {
    float gm = gamma[g * 16 + c];
    ga[c] = gm * rstd;
    be[c] = beta[g * 16 + c] - mean * gm * rstd;
  }
  __shared__ float tile[16][260];
  for (int lc = 0; lc < 8; ++lc) {
    __syncthreads();
#pragma unroll
    for (int it = 0; it < 4; ++it) {
      int r = it * 4 + w;
      int c4 = (t & 63) * 4;
      *(float4*)&tile[r][c4] = *(const float4*)(base + (size_t)r * L_SEQ + lc * 256 + c4);
    }
    __syncthreads();
    int l = lc * 256 + t;
    unsigned wds[8];
#pragma unroll
    for (int c = 0; c < 8; ++c) {
      float a0 = tile[2 * c][t] * ga[2 * c] + be[2 * c];
      float a1 = tile[2 * c + 1][t] * ga[2 * c + 1] + be[2 * c + 1];
      wds[c] = (unsigned)f2bf(a0) | ((unsigned)f2bf(a1) << 16);
    }
    u16* dst = h_t + ((size_t)(b * L_SEQ + l)) * C_DIM + g * 16;
    uint4 p0; p0.x = wds[0]; p0.y = wds[1]; p0.z = wds[2]; p0.w = wds[3];
    uint4 p1; p1.x = wds[4]; p1.y = wds[5]; p1.z = wds[6]; p1.w = wds[7];
    *(uint4*)dst = p0;
    *(uint4*)(dst + 8) = p1;
  }
}

// ---------------------------------------------------------------- GEMM
// MODE 0: qkv = Wqkv(1536x512) @ h_b(512xL) + bias  -> q_t,k_t (b,l,c) ; v_c (b,c,l)
// MODE 1: out = Wproj(512x512) @ ao_b(512xL) + bias + x   (fp32, (b,c,l))
template <int MODE>
__global__ __launch_bounds__(256) void gemm_kernel(const u16* __restrict__ A_bf,
                                                   const u16* __restrict__ B_t,
                                                   const float* __restrict__ bias,
                                                   const float* __restrict__ xres,
                                                   u16* __restrict__ q_t,
                                                   u16* __restrict__ k_t,
                                                   u16* __restrict__ v_c,
                                                   float* __restrict__ out_f) {
  constexpr int K = 512;
  __shared__ u16 A_lds[128][40];
  __shared__ u16 B_lds[128][40];
  int t = threadIdx.x;
  int w = t >> 6, lane = t & 63;
  int q4 = lane >> 4, c15 = lane & 15;
  int wm = w >> 1, wn = w & 1;
  int o0 = blockIdx.y * 128;
  int l0 = blockIdx.x * 128;
  int b = blockIdx.z;
  const u16* Bb = B_t + (size_t)b * L_SEQ * K;
  f32x4 acc[4][4] = {};
  int srow = t >> 2;
  int scol = (t & 3) * 8;
  const u16* Ap = A_bf + (size_t)(o0 + srow) * K + scol;
  const u16* Bp = Bb + (size_t)(l0 + srow) * K + scol;
  for (int kt = 0; kt < K / 32; ++kt) {
    __syncthreads();
    *(uint4*)&A_lds[srow][scol] = *(const uint4*)(Ap);
    *(uint4*)&A_lds[srow + 64][scol] = *(const uint4*)(Ap + (size_t)64 * K);
    *(uint4*)&B_lds[srow][scol] = *(const uint4*)(Bp);
    *(uint4*)&B_lds[srow + 64][scol] = *(const uint4*)(Bp + (size_t)64 * K);
    Ap += 32; Bp += 32;
    __syncthreads();
    bf16x8 af[4], bfr[4];
#pragma unroll
    for (int mi = 0; mi < 4; ++mi) af[mi] = *(const bf16x8*)&A_lds[wm * 64 + mi * 16 + c15][q4 * 8];
#pragma unroll
    for (int ni = 0; ni < 4; ++ni) bfr[ni] = *(const bf16x8*)&B_lds[wn * 64 + ni * 16 + c15][q4 * 8];
#pragma unroll
    for (int mi = 0; mi < 4; ++mi)
#pragma unroll
      for (int ni = 0; ni < 4; ++ni)
        acc[mi][ni] = __builtin_amdgcn_mfma_f32_16x16x32_bf16(af[mi], bfr[ni], acc[mi][ni], 0, 0, 0);
  }

  if (MODE == 0) {
    int sel = o0 >> 9;  // 0=q 1=k 2=v
    int ob = o0 - sel * 512 + wm * 64;
    u16* qk = (sel == 0) ? q_t : k_t;
#pragma unroll
    for (int mi = 0; mi < 4; ++mi) {
      int orow = ob + mi * 16 + q4 * 4;
      float4 bi = *(const float4*)&bias[o0 + wm * 64 + mi * 16 + q4 * 4];
#pragma unroll
      for (int ni = 0; ni < 4; ++ni) {
        int l = l0 + wn * 64 + ni * 16 + c15;
        float v0 = acc[mi][ni][0] + bi.x;
        float v1 = acc[mi][ni][1] + bi.y;
        float v2 = acc[mi][ni][2] + bi.z;
        float v3 = acc[mi][ni][3] + bi.w;
        if (sel < 2) {
          uint2 pk;
          pk.x = (unsigned)f2bf(v0) | ((unsigned)f2bf(v1) << 16);
          pk.y = (unsigned)f2bf(v2) | ((unsigned)f2bf(v3) << 16);
          *(uint2*)(qk + ((size_t)(b * L_SEQ + l)) * C_DIM + orow) = pk;
        } else {
          size_t base2 = ((size_t)(b * C_DIM + orow)) * L_SEQ + l;
          v_c[base2] = f2bf(v0);
          v_c[base2 + L_SEQ] = f2bf(v1);
          v_c[base2 + 2 * L_SEQ] = f2bf(v2);
          v_c[base2 + 3 * L_SEQ] = f2bf(v3);
        }
      }
    }
  } else {
#pragma unroll
    for (int mi = 0; mi < 4; ++mi) {
      int orow = o0 + wm * 64 + mi * 16 + q4 * 4;
      float4 bi = *(const float4*)&bias[orow];
#pragma unroll
      for (int ni = 0; ni < 4; ++ni) {
        int l = l0 + wn * 64 + ni * 16 + c15;
        size_t base2 = ((size_t)(b * C_DIM + orow)) * L_SEQ + l;
        out_f[base2] = acc[mi][ni][0] + bi.x + xres[base2];
        out_f[base2 + L_SEQ] = acc[mi][ni][1] + bi.y + xres[base2 + L_SEQ];
        out_f[base2 + 2 * L_SEQ] = acc[mi][ni][2] + bi.z + xres[base2 + 2 * L_SEQ];
        out_f[base2 + 3 * L_SEQ] = acc[mi][ni][3] + bi.w + xres[base2 + 3 * L_SEQ];
      }
    }
  }
}

// ---------------------------------------------------------------- attention
// grid (L/128, B*H). 4 waves x 32 q-rows. KV tiles of 64. Online softmax.
__global__ __launch_bounds__(256) void attn_kernel(const u16* __restrict__ q_t,
                                                   const u16* __restrict__ k_t,
                                                   const u16* __restrict__ v_c,
                                                   u16* __restrict__ ao_t) {
  __shared__ u16 K_lds[64][72];
  __shared__ u16 V_lds[64][72];
  __shared__ u16 P_lds[4][32][72];
  int t = threadIdx.x;
  int w = t >> 6, lane = t & 63;
  int q4 = lane >> 4, c15 = lane & 15;
  int bh = blockIdx.y;
  int b = bh >> 3, h = bh & 7;
  int q0 = blockIdx.x * 128 + w * 32;
  const float SC = 0.125f * 1.44269504f;  // scale * log2(e)

  bf16x8 qa[2][2];
#pragma unroll
  for (int mi = 0; mi < 2; ++mi)
#pragma unroll
    for (int kk = 0; kk < 2; ++kk)
      qa[mi][kk] = *(const bf16x8*)(q_t + ((size_t)(b * L_SEQ + q0 + mi * 16 + c15)) * C_DIM +
                                    h * 64 + kk * 32 + q4 * 8);
  f32x4 o_acc[2][4] = {};
  float m_r[2][4], l_r[2][4];
#pragma unroll
  for (int mi = 0; mi < 2; ++mi)
#pragma unroll
    for (int r = 0; r < 4; ++r) { m_r[mi][r] = -1e30f; l_r[mi][r] = 0.f; }

  int sr = t >> 3;
  int sc = (t & 7) * 8;
  for (int kt = 0; kt < L_SEQ / 64; ++kt) {
    __syncthreads();
    int lk0 = kt * 64;
    *(uint4*)&K_lds[sr][sc] = *(const uint4*)(k_t + ((size_t)(b * L_SEQ + lk0 + sr)) * C_DIM + h * 64 + sc);
    *(uint4*)&K_lds[sr + 32][sc] = *(const uint4*)(k_t + ((size_t)(b * L_SEQ + lk0 + sr + 32)) * C_DIM + h * 64 + sc);
    *(uint4*)&V_lds[sr][sc] = *(const uint4*)(v_c + ((size_t)(b * C_DIM + h * 64 + sr)) * L_SEQ + lk0 + sc);
    *(uint4*)&V_lds[sr + 32][sc] = *(const uint4*)(v_c + ((size_t)(b * C_DIM + h * 64 + sr + 32)) * L_SEQ + lk0 + sc);
    __syncthreads();

    f32x4 s[2][4] = {};
#pragma unroll
    for (int kk = 0; kk < 2; ++kk) {
#pragma unroll
      for (int nj = 0; nj < 4; ++nj) {
        bf16x8 kb = *(const bf16x8*)&K_lds[nj * 16 + c15][kk * 32 + q4 * 8];
#pragma unroll
        for (int mi = 0; mi < 2; ++mi)
          s[mi][nj] = __builtin_amdgcn_mfma_f32_16x16x32_bf16(qa[mi][kk], kb, s[mi][nj], 0, 0, 0);
      }
    }

#pragma unroll
    for (int mi = 0; mi < 2; ++mi) {
#pragma unroll
      for (int r = 0; r < 4; ++r) {
        float mx = fmaxf(fmaxf(s[mi][0][r], s[mi][1][r]), fmaxf(s[mi][2][r], s[mi][3][r]));
        mx = fmaxf(mx, __shfl_xor(mx, 1));
        mx = fmaxf(mx, __shfl_xor(mx, 2));
        mx = fmaxf(mx, __shfl_xor(mx, 4));
        mx = fmaxf(mx, __shfl_xor(mx, 8));
        float mold = m_r[mi][r];
        float mnew = fmaxf(mold, mx);
        float alpha = exp2f((mold - mnew) * SC);
        m_r[mi][r] = mnew;
        float sum = 0.f;
#pragma unroll
        for (int nj = 0; nj < 4; ++nj) {
          float p = exp2f((s[mi][nj][r] - mnew) * SC);
          s[mi][nj][r] = p;
          sum += p;
        }
        sum += __shfl_xor(sum, 1);
        sum += __shfl_xor(sum, 2);
        sum += __shfl_xor(sum, 4);
        sum += __shfl_xor(sum, 8);
        l_r[mi][r] = l_r[mi][r] * alpha + sum;
#pragma unroll
        for (int nd = 0; nd < 4; ++nd) o_acc[mi][nd][r] *= alpha;
      }
    }

#pragma unroll
    for (int mi = 0; mi < 2; ++mi)
#pragma unroll
      for (int nj = 0; nj < 4; ++nj)
#pragma unroll
        for (int r = 0; r < 4; ++r)
          P_lds[w][mi * 16 + q4 * 4 + r][nj * 16 + c15] = f2bf(s[mi][nj][r]);

#pragma unroll
    for (int kk = 0; kk < 2; ++kk) {
      bf16x8 pa[2];
#pragma unroll
      for (int mi = 0; mi < 2; ++mi) pa[mi] = *(const bf16x8*)&P_lds[w][mi * 16 + c15][kk * 32 + q4 * 8];
#pragma unroll
      for (int nd = 0; nd < 4; ++nd) {
        bf16x8 vb = *(const bf16x8*)&V_lds[nd * 16 + c15][kk * 32 + q4 * 8];
#pragma unroll
        for (int mi = 0; mi < 2; ++mi)
          o_acc[mi][nd] = __builtin_amdgcn_mfma_f32_16x16x32_bf16(pa[mi], vb, o_acc[mi][nd], 0, 0, 0);
      }
    }
  }

#pragma unroll
  for (int mi = 0; mi < 2; ++mi) {
#pragma unroll
    for (int r = 0; r < 4; ++r) {
      float inv = 1.f / l_r[mi][r];
      int l = q0 + mi * 16 + q4 * 4 + r;
      u16* dst = ao_t + ((size_t)(b * L_SEQ + l)) * C_DIM + h * 64;
#pragma unroll
      for (int nd = 0; nd < 4; ++nd) dst[nd * 16 + c15] = f2bf(o_acc[mi][nd][r] * inv);
    }
  }
}

// ---------------------------------------------------------------- launch
extern "C" void kernel_launch(void* const* d_in, const int* in_sizes, int n_in,
                              void* d_out, int out_size, void* d_ws, size_t ws_size,
                              hipStream_t stream) {
  const float* x = (const float*)d_in[0];
  const float* gamma = (const float*)d_in[1];
  const float* beta = (const float*)d_in[2];
  const float* w_qkv = (const float*)d_in[3];
  const float* b_qkv = (const float*)d_in[4];
  const float* w_proj = (const float*)d_in[5];
  const float* b_proj = (const float*)d_in[6];
  float* out = (float*)d_out;

  u16* wq_bf = (u16*)d_ws;                 // 786432
  u16* wp_bf = wq_bf + 786432;             // 262144
  u16* h_t = wp_bf + 262144;               // 4194304 (b,l,c)
  u16* q_t = h_t + 4194304;                // (b,l,c)
  u16* k_t = q_t + 4194304;                // (b,l,c)
  u16* v_c = k_t + 4194304;                // (b,c,l)
  u16* ao_t = v_c + 4194304;               // (b,l,c)

  cvt_weights<<<dim3(1024), dim3(256), 0, stream>>>(w_qkv, w_proj, wq_bf, wp_bf);
  groupnorm_kernel<<<dim3(128), dim3(256), 0, stream>>>(x, gamma, beta, h_t);
  gemm_kernel<0><<<dim3(16, 12, 4), dim3(256), 0, stream>>>(wq_bf, h_t, b_qkv, nullptr, q_t, k_t, v_c, nullptr);
  attn_kernel<<<dim3(16, 32), dim3(256), 0, stream>>>(q_t, k_t, v_c, ao_t);
  gemm_kernel<1><<<dim3(16, 4, 4), dim3(256), 0, stream>>>(wp_bf, ao_t, b_proj, x, nullptr, nullptr, nullptr, out);
}

// Round 2
// 184.065 us; speedup vs baseline: 1.2797x; 1.2797x over previous
//
#include <hip/hip_runtime.h>
#include <stdint.h>

#define C_DIM 512
#define H_HEADS 8
#define D_HEAD 64
#define B_BATCH 4
#define L_SEQ 2048
#define GROUPS 32
#define EPS_GN 1e-5f

typedef unsigned short u16;
typedef __attribute__((ext_vector_type(8))) __bf16 bf16x8;
typedef __attribute__((ext_vector_type(4))) float f32x4;
typedef __attribute__((ext_vector_type(16))) float f32x16;

__device__ __forceinline__ u16 f2bf(float f) {
  unsigned u = __builtin_bit_cast(unsigned, f);
  unsigned r = u + 0x7FFFu + ((u >> 16) & 1u);
  return (u16)(r >> 16);
}

__device__ __forceinline__ unsigned cvtpk_bf16(float lo, float hi) {
  unsigned r;
  asm("v_cvt_pk_bf16_f32 %0, %1, %2" : "=v"(r) : "v"(lo), "v"(hi));
  return r;
}

__device__ __forceinline__ void pl32swap(unsigned& a, unsigned& b) {
  asm("v_permlane32_swap_b32 %0, %1" : "+v"(a), "+v"(b));
}

__device__ __forceinline__ bf16x8 mk8(unsigned a, unsigned b, unsigned c, unsigned d) {
  union { uint4 u; bf16x8 v; } z;
  z.u.x = a; z.u.y = b; z.u.z = c; z.u.w = d;
  return z.v;
}

// ---------------------------------------------------------------- weights cvt
__global__ __launch_bounds__(256) void cvt_weights(const float* __restrict__ wq,
                                                   const float* __restrict__ wp,
                                                   u16* __restrict__ wq_bf,
                                                   u16* __restrict__ wp_bf) {
  int i = blockIdx.x * 256 + threadIdx.x;
  const int nq = 3 * C_DIM * C_DIM;
  int idx = i * 4;
  const float* src;
  u16* dst;
  if (idx < nq) { src = wq + idx; dst = wq_bf + idx; }
  else          { src = wp + (idx - nq); dst = wp_bf + (idx - nq); }
  float4 v = *(const float4*)src;
  uint2 pk;
  pk.x = (unsigned)f2bf(v.x) | ((unsigned)f2bf(v.y) << 16);
  pk.y = (unsigned)f2bf(v.z) | ((unsigned)f2bf(v.w) << 16);
  *(uint2*)dst = pk;
}

// ---------------------------------------------------------------- group norm
__global__ __launch_bounds__(256) void groupnorm_kernel(const float* __restrict__ x,
                                                        const float* __restrict__ gamma,
                                                        const float* __restrict__ beta,
                                                        u16* __restrict__ h_t) {
  int bg = blockIdx.x;
  int b = bg >> 5, g = bg & 31;
  const float* base = x + ((size_t)(b * C_DIM + g * 16)) * L_SEQ;
  int t = threadIdx.x;
  int w = t >> 6;
  float s = 0.f, sq = 0.f;
  for (int i = 0; i < 32; ++i) {
    float4 v = ((const float4*)base)[t + i * 256];
    s += v.x + v.y + v.z + v.w;
    sq += v.x * v.x + v.y * v.y + v.z * v.z + v.w * v.w;
  }
  for (int off = 32; off; off >>= 1) { s += __shfl_down(s, off); sq += __shfl_down(sq, off); }
  __shared__ float red[8];
  if ((t & 63) == 0) { red[w * 2] = s; red[w * 2 + 1] = sq; }
  __syncthreads();
  float ts = red[0] + red[2] + red[4] + red[6];
  float tq = red[1] + red[3] + red[5] + red[7];
  float mean = ts * (1.f / 32768.f);
  float var = tq * (1.f / 32768.f) - mean * mean;
  float rstd = rsqrtf(var + EPS_GN);
  float ga[16], be[16];
#pragma unroll
  for (int c = 0; c < 16; ++c) {
    float gm = gamma[g * 16 + c];
    ga[c] = gm * rstd;
    be[c] = beta[g * 16 + c] - mean * gm * rstd;
  }
  __shared__ float tile[16][260];
  for (int lc = 0; lc < 8; ++lc) {
    __syncthreads();
#pragma unroll
    for (int it = 0; it < 4; ++it) {
      int r = it * 4 + w;
      int c4 = (t & 63) * 4;
      *(float4*)&tile[r][c4] = *(const float4*)(base + (size_t)r * L_SEQ + lc * 256 + c4);
    }
    __syncthreads();
    int l = lc * 256 + t;
    unsigned wds[8];
#pragma unroll
    for (int c = 0; c < 8; ++c) {
      float a0 = tile[2 * c][t] * ga[2 * c] + be[2 * c];
      float a1 = tile[2 * c + 1][t] * ga[2 * c + 1] + be[2 * c + 1];
      wds[c] = (unsigned)f2bf(a0) | ((unsigned)f2bf(a1) << 16);
    }
    u16* dst = h_t + ((size_t)(b * L_SEQ + l)) * C_DIM + g * 16;
    uint4 p0; p0.x = wds[0]; p0.y = wds[1]; p0.z = wds[2]; p0.w = wds[3];
    uint4 p1; p1.x = wds[4]; p1.y = wds[5]; p1.z = wds[6]; p1.w = wds[7];
    *(uint4*)dst = p0;
    *(uint4*)(dst + 8) = p1;
  }
}

// ---------------------------------------------------------------- GEMM
// MODE 0: qkv = Wqkv(1536x512) @ h + bias -> q_t (scaled), k_t (b,l,c); v_c (b,c,l)
// MODE 1: out = Wproj(512x512) @ ao + bias + x  (fp32, (b,c,l))
template <int MODE>
__global__ __launch_bounds__(256) void gemm_kernel(const u16* __restrict__ A_bf,
                                                   const u16* __restrict__ B_t,
                                                   const float* __restrict__ bias,
                                                   const float* __restrict__ xres,
                                                   u16* __restrict__ q_t,
                                                   u16* __restrict__ k_t,
                                                   u16* __restrict__ v_c,
                                                   float* __restrict__ out_f) {
  constexpr int K = 512;
  __shared__ u16 A_lds[128][40];
  __shared__ u16 B_lds[128][40];
  int t = threadIdx.x;
  int w = t >> 6, lane = t & 63;
  int q4 = lane >> 4, c15 = lane & 15;
  int wm = w >> 1, wn = w & 1;
  int o0 = blockIdx.y * 128;
  int l0 = blockIdx.x * 128;
  int b = blockIdx.z;
  const u16* Bb = B_t + (size_t)b * L_SEQ * K;
  f32x4 acc[4][4] = {};
  int srow = t >> 2;
  int scol = (t & 3) * 8;
  const u16* Ap = A_bf + (size_t)(o0 + srow) * K + scol;
  const u16* Bp = Bb + (size_t)(l0 + srow) * K + scol;
  for (int kt = 0; kt < K / 32; ++kt) {
    __syncthreads();
    *(uint4*)&A_lds[srow][scol] = *(const uint4*)(Ap);
    *(uint4*)&A_lds[srow + 64][scol] = *(const uint4*)(Ap + (size_t)64 * K);
    *(uint4*)&B_lds[srow][scol] = *(const uint4*)(Bp);
    *(uint4*)&B_lds[srow + 64][scol] = *(const uint4*)(Bp + (size_t)64 * K);
    Ap += 32; Bp += 32;
    __syncthreads();
    bf16x8 af[4], bfr[4];
#pragma unroll
    for (int mi = 0; mi < 4; ++mi) af[mi] = *(const bf16x8*)&A_lds[wm * 64 + mi * 16 + c15][q4 * 8];
#pragma unroll
    for (int ni = 0; ni < 4; ++ni) bfr[ni] = *(const bf16x8*)&B_lds[wn * 64 + ni * 16 + c15][q4 * 8];
#pragma unroll
    for (int mi = 0; mi < 4; ++mi)
#pragma unroll
      for (int ni = 0; ni < 4; ++ni)
        acc[mi][ni] = __builtin_amdgcn_mfma_f32_16x16x32_bf16(af[mi], bfr[ni], acc[mi][ni], 0, 0, 0);
  }

  if (MODE == 0) {
    const float QS = 0.18033688f;  // 0.125 * log2(e) folded into Q
    int sel = o0 >> 9;
    int ob = o0 - sel * 512 + wm * 64;
    u16* qk = (sel == 0) ? q_t : k_t;
#pragma unroll
    for (int mi = 0; mi < 4; ++mi) {
      int orow = ob + mi * 16 + q4 * 4;
      float4 bi = *(const float4*)&bias[o0 + wm * 64 + mi * 16 + q4 * 4];
#pragma unroll
      for (int ni = 0; ni < 4; ++ni) {
        int l = l0 + wn * 64 + ni * 16 + c15;
        float v0 = acc[mi][ni][0] + bi.x;
        float v1 = acc[mi][ni][1] + bi.y;
        float v2 = acc[mi][ni][2] + bi.z;
        float v3 = acc[mi][ni][3] + bi.w;
        if (sel == 0) { v0 *= QS; v1 *= QS; v2 *= QS; v3 *= QS; }
        if (sel < 2) {
          uint2 pk;
          pk.x = (unsigned)f2bf(v0) | ((unsigned)f2bf(v1) << 16);
          pk.y = (unsigned)f2bf(v2) | ((unsigned)f2bf(v3) << 16);
          *(uint2*)(qk + ((size_t)(b * L_SEQ + l)) * C_DIM + orow) = pk;
        } else {
          size_t base2 = ((size_t)(b * C_DIM + orow)) * L_SEQ + l;
          v_c[base2] = f2bf(v0);
          v_c[base2 + L_SEQ] = f2bf(v1);
          v_c[base2 + 2 * L_SEQ] = f2bf(v2);
          v_c[base2 + 3 * L_SEQ] = f2bf(v3);
        }
      }
    }
  } else {
#pragma unroll
    for (int mi = 0; mi < 4; ++mi) {
      int orow = o0 + wm * 64 + mi * 16 + q4 * 4;
      float4 bi = *(const float4*)&bias[orow];
#pragma unroll
      for (int ni = 0; ni < 4; ++ni) {
        int l = l0 + wn * 64 + ni * 16 + c15;
        size_t base2 = ((size_t)(b * C_DIM + orow)) * L_SEQ + l;
        out_f[base2] = acc[mi][ni][0] + bi.x + xres[base2];
        out_f[base2 + L_SEQ] = acc[mi][ni][1] + bi.y + xres[base2 + L_SEQ];
        out_f[base2 + 2 * L_SEQ] = acc[mi][ni][2] + bi.z + xres[base2 + 2 * L_SEQ];
        out_f[base2 + 3 * L_SEQ] = acc[mi][ni][3] + bi.w + xres[base2 + 3 * L_SEQ];
      }
    }
  }
}

// ---------------------------------------------------------------- attention
// Swapped-operand flash attention, 32x32x16 MFMA, no LDS, no barriers.
// 4 waves x 32 q-rows per block; KV tile = 64. Q pre-scaled by 0.125*log2e.
__global__ __launch_bounds__(256) void attn_kernel(const u16* __restrict__ q_t,
                                                   const u16* __restrict__ k_t,
                                                   const u16* __restrict__ v_c,
                                                   u16* __restrict__ ao_t) {
  int g = blockIdx.x;
  int wk = (g & 7) * 64 + (g >> 3);  // XCD swizzle: 512 wgs, 8 XCDs
  int qb = wk & 15, bh = wk >> 4;
  int b = bh >> 3, h = bh & 7;
  int t = threadIdx.x;
  int wv = t >> 6, lane = t & 63;
  int q = lane & 31, hi = lane >> 5;
  int q0 = qb * 128 + wv * 32;

  // Q fragments (B-operand: col=q, k = c = kk*16 + hi*8 + j)
  const u16* qp = q_t + ((size_t)(b * L_SEQ + q0 + q)) * C_DIM + h * 64 + hi * 8;
  bf16x8 qf[4];
#pragma unroll
  for (int kk = 0; kk < 4; ++kk) qf[kk] = *(const bf16x8*)(qp + kk * 16);

  f32x16 o0, o1;
#pragma unroll
  for (int r = 0; r < 16; ++r) { o0[r] = 0.f; o1[r] = 0.f; }
  float m_r = -1e30f, l_r = 0.f;

  const u16* kb0 = k_t + ((size_t)(b * L_SEQ + q)) * C_DIM + h * 64 + hi * 8;
  const u16* vb0 = v_c + ((size_t)(b * C_DIM + h * 64 + q)) * L_SEQ + hi * 8;

  for (int kt = 0; kt < L_SEQ / 64; ++kt) {
    int kv0 = kt * 64;
    bf16x8 kf0[4], kf1[4], vf0[4], vf1[4];
#pragma unroll
    for (int kk = 0; kk < 4; ++kk) {
      kf0[kk] = *(const bf16x8*)(kb0 + (size_t)(kv0)*C_DIM + kk * 16);
      kf1[kk] = *(const bf16x8*)(kb0 + (size_t)(kv0 + 32) * C_DIM + kk * 16);
      vf0[kk] = *(const bf16x8*)(vb0 + kv0 + kk * 16);
      vf1[kk] = *(const bf16x8*)(vb0 + (size_t)32 * L_SEQ + kv0 + kk * 16);
    }
    // S^T = K * Q^T : col = q (lane&31), reg r -> kv = sub*32 + (r&3)+8*(r>>2)+4*hi
    f32x16 sa, sb;
#pragma unroll
    for (int r = 0; r < 16; ++r) { sa[r] = 0.f; sb[r] = 0.f; }
#pragma unroll
    for (int kk = 0; kk < 4; ++kk) {
      sa = __builtin_amdgcn_mfma_f32_32x32x16_bf16(kf0[kk], qf[kk], sa, 0, 0, 0);
      sb = __builtin_amdgcn_mfma_f32_32x32x16_bf16(kf1[kk], qf[kk], sb, 0, 0, 0);
    }

    // in-lane row softmax (exp2 domain; scale folded into Q)
    float mx = sa[0];
#pragma unroll
    for (int r = 1; r < 16; ++r) mx = fmaxf(mx, sa[r]);
#pragma unroll
    for (int r = 0; r < 16; ++r) mx = fmaxf(mx, sb[r]);
    mx = fmaxf(mx, __shfl_xor(mx, 32));
    if (__any(mx > m_r + 8.f)) {  // defer-max, THR=8 -> p <= 256
      float mnew = fmaxf(m_r, mx);
      float al = __builtin_amdgcn_exp2f(m_r - mnew);
      l_r *= al;
#pragma unroll
      for (int r = 0; r < 16; ++r) { o0[r] *= al; o1[r] *= al; }
      m_r = mnew;
    }
    float sum = 0.f;
#pragma unroll
    for (int r = 0; r < 16; ++r) { sa[r] = __builtin_amdgcn_exp2f(sa[r] - m_r); sum += sa[r]; }
#pragma unroll
    for (int r = 0; r < 16; ++r) { sb[r] = __builtin_amdgcn_exp2f(sb[r] - m_r); sum += sb[r]; }
    sum += __shfl_xor(sum, 32);
    l_r += sum;

    // P^T -> bf16 fragments for PV (B-operand: col=q, k=kv)
    unsigned pka[8], pkb[8];
#pragma unroll
    for (int i = 0; i < 8; ++i) {
      pka[i] = cvtpk_bf16(sa[2 * i], sa[2 * i + 1]);
      pkb[i] = cvtpk_bf16(sb[2 * i], sb[2 * i + 1]);
    }
    pl32swap(pka[0], pka[2]); pl32swap(pka[1], pka[3]);
    pl32swap(pka[4], pka[6]); pl32swap(pka[5], pka[7]);
    pl32swap(pkb[0], pkb[2]); pl32swap(pkb[1], pkb[3]);
    pl32swap(pkb[4], pkb[6]); pl32swap(pkb[5], pkb[7]);
    bf16x8 pf0 = mk8(pka[0], pka[1], pka[2], pka[3]);
    bf16x8 pf1 = mk8(pka[4], pka[5], pka[6], pka[7]);
    bf16x8 pf2 = mk8(pkb[0], pkb[1], pkb[2], pkb[3]);
    bf16x8 pf3 = mk8(pkb[4], pkb[5], pkb[6], pkb[7]);

    // out^T = V^T * P^T : col = q, reg r -> d = n*32 + (r&3)+8*(r>>2)+4*hi
    o0 = __builtin_amdgcn_mfma_f32_32x32x16_bf16(vf0[0], pf0, o0, 0, 0, 0);
    o1 = __builtin_amdgcn_mfma_f32_32x32x16_bf16(vf1[0], pf0, o1, 0, 0, 0);
    o0 = __builtin_amdgcn_mfma_f32_32x32x16_bf16(vf0[1], pf1, o0, 0, 0, 0);
    o1 = __builtin_amdgcn_mfma_f32_32x32x16_bf16(vf1[1], pf1, o1, 0, 0, 0);
    o0 = __builtin_amdgcn_mfma_f32_32x32x16_bf16(vf0[2], pf2, o0, 0, 0, 0);
    o1 = __builtin_amdgcn_mfma_f32_32x32x16_bf16(vf1[2], pf2, o1, 0, 0, 0);
    o0 = __builtin_amdgcn_mfma_f32_32x32x16_bf16(vf0[3], pf3, o0, 0, 0, 0);
    o1 = __builtin_amdgcn_mfma_f32_32x32x16_bf16(vf1[3], pf3, o1, 0, 0, 0);
  }

  float inv = 1.f / l_r;
  u16* dst = ao_t + ((size_t)(b * L_SEQ + q0 + q)) * C_DIM + h * 64;
#pragma unroll
  for (int tq = 0; tq < 4; ++tq) {
    uint2 w0, w1;
    w0.x = cvtpk_bf16(o0[4 * tq] * inv, o0[4 * tq + 1] * inv);
    w0.y = cvtpk_bf16(o0[4 * tq + 2] * inv, o0[4 * tq + 3] * inv);
    *(uint2*)(dst + 8 * tq + 4 * hi) = w0;
    w1.x = cvtpk_bf16(o1[4 * tq] * inv, o1[4 * tq + 1] * inv);
    w1.y = cvtpk_bf16(o1[4 * tq + 2] * inv, o1[4 * tq + 3] * inv);
    *(uint2*)(dst + 32 + 8 * tq + 4 * hi) = w1;
  }
}

// ---------------------------------------------------------------- launch
extern "C" void kernel_launch(void* const* d_in, const int* in_sizes, int n_in,
                              void* d_out, int out_size, void* d_ws, size_t ws_size,
                              hipStream_t stream) {
  const float* x = (const float*)d_in[0];
  const float* gamma = (const float*)d_in[1];
  const float* beta = (const float*)d_in[2];
  const float* w_qkv = (const float*)d_in[3];
  const float* b_qkv = (const float*)d_in[4];
  const float* w_proj = (const float*)d_in[5];
  const float* b_proj = (const float*)d_in[6];
  float* out = (float*)d_out;

  u16* wq_bf = (u16*)d_ws;                 // 786432
  u16* wp_bf = wq_bf + 786432;             // 262144
  u16* h_t = wp_bf + 262144;               // 4194304 (b,l,c)
  u16* q_t = h_t + 4194304;                // (b,l,c), pre-scaled
  u16* k_t = q_t + 4194304;                // (b,l,c)
  u16* v_c = k_t + 4194304;                // (b,c,l)
  u16* ao_t = v_c + 4194304;               // (b,l,c)

  cvt_weights<<<dim3(1024), dim3(256), 0, stream>>>(w_qkv, w_proj, wq_bf, wp_bf);
  groupnorm_kernel<<<dim3(128), dim3(256), 0, stream>>>(x, gamma, beta, h_t);
  gemm_kernel<0><<<dim3(16, 12, 4), dim3(256), 0, stream>>>(wq_bf, h_t, b_qkv, nullptr, q_t, k_t, v_c, nullptr);
  attn_kernel<<<dim3(512), dim3(256), 0, stream>>>(q_t, k_t, v_c, ao_t);
  gemm_kernel<1><<<dim3(16, 4, 4), dim3(256), 0, stream>>>(wp_bf, ao_t, b_proj, x, nullptr, nullptr, nullptr, out);
}

// Round 3
// 125.316 us; speedup vs baseline: 1.8796x; 1.4688x over previous
//
#include <hip/hip_runtime.h>
#include <stdint.h>

#define C_DIM 512
#define H_HEADS 8
#define D_HEAD 64
#define B_BATCH 4
#define L_SEQ 2048
#define GROUPS 32
#define EPS_GN 1e-5f

typedef unsigned short u16;
typedef __attribute__((ext_vector_type(8))) __bf16 bf16x8;
typedef __attribute__((ext_vector_type(4))) float f32x4;
typedef __attribute__((ext_vector_type(16))) float f32x16;

__device__ __forceinline__ u16 f2bf(float f) {
  unsigned u = __builtin_bit_cast(unsigned, f);
  unsigned r = u + 0x7FFFu + ((u >> 16) & 1u);
  return (u16)(r >> 16);
}

__device__ __forceinline__ unsigned cvtpk_bf16(float lo, float hi) {
  unsigned r;
  asm("v_cvt_pk_bf16_f32 %0, %1, %2" : "=v"(r) : "v"(lo), "v"(hi));
  return r;
}

__device__ __forceinline__ void pl32swap(unsigned& a, unsigned& b) {
  asm("v_permlane32_swap_b32 %0, %1" : "+v"(a), "+v"(b));
}

__device__ __forceinline__ bf16x8 mk8(unsigned a, unsigned b, unsigned c, unsigned d) {
  union { uint4 u; bf16x8 v; } z;
  z.u.x = a; z.u.y = b; z.u.z = c; z.u.w = d;
  return z.v;
}

// ---------------------------------------------------------------- weights cvt
__global__ __launch_bounds__(256) void cvt_weights(const float* __restrict__ wq,
                                                   const float* __restrict__ wp,
                                                   u16* __restrict__ wq_bf,
                                                   u16* __restrict__ wp_bf) {
  int i = blockIdx.x * 256 + threadIdx.x;
  const int nq = 3 * C_DIM * C_DIM;
  int idx = i * 4;
  const float* src;
  u16* dst;
  if (idx < nq) { src = wq + idx; dst = wq_bf + idx; }
  else          { src = wp + (idx - nq); dst = wp_bf + (idx - nq); }
  float4 v = *(const float4*)src;
  uint2 pk;
  pk.x = (unsigned)f2bf(v.x) | ((unsigned)f2bf(v.y) << 16);
  pk.y = (unsigned)f2bf(v.z) | ((unsigned)f2bf(v.w) << 16);
  *(uint2*)dst = pk;
}

// ---------------------------------------------------------------- group norm
__global__ __launch_bounds__(256) void groupnorm_kernel(const float* __restrict__ x,
                                                        const float* __restrict__ gamma,
                                                        const float* __restrict__ beta,
                                                        u16* __restrict__ h_t) {
  int bg = blockIdx.x;
  int b = bg >> 5, g = bg & 31;
  const float* base = x + ((size_t)(b * C_DIM + g * 16)) * L_SEQ;
  int t = threadIdx.x;
  int w = t >> 6;
  float s = 0.f, sq = 0.f;
  for (int i = 0; i < 32; ++i) {
    float4 v = ((const float4*)base)[t + i * 256];
    s += v.x + v.y + v.z + v.w;
    sq += v.x * v.x + v.y * v.y + v.z * v.z + v.w * v.w;
  }
  for (int off = 32; off; off >>= 1) { s += __shfl_down(s, off); sq += __shfl_down(sq, off); }
  __shared__ float red[8];
  if ((t & 63) == 0) { red[w * 2] = s; red[w * 2 + 1] = sq; }
  __syncthreads();
  float ts = red[0] + red[2] + red[4] + red[6];
  float tq = red[1] + red[3] + red[5] + red[7];
  float mean = ts * (1.f / 32768.f);
  float var = tq * (1.f / 32768.f) - mean * mean;
  float rstd = rsqrtf(var + EPS_GN);
  float ga[16], be[16];
#pragma unroll
  for (int c = 0; c < 16; ++c) {
    float gm = gamma[g * 16 + c];
    ga[c] = gm * rstd;
    be[c] = beta[g * 16 + c] - mean * gm * rstd;
  }
  __shared__ float tile[16][260];
  for (int lc = 0; lc < 8; ++lc) {
    __syncthreads();
#pragma unroll
    for (int it = 0; it < 4; ++it) {
      int r = it * 4 + w;
      int c4 = (t & 63) * 4;
      *(float4*)&tile[r][c4] = *(const float4*)(base + (size_t)r * L_SEQ + lc * 256 + c4);
    }
    __syncthreads();
    int l = lc * 256 + t;
    unsigned wds[8];
#pragma unroll
    for (int c = 0; c < 8; ++c) {
      float a0 = tile[2 * c][t] * ga[2 * c] + be[2 * c];
      float a1 = tile[2 * c + 1][t] * ga[2 * c + 1] + be[2 * c + 1];
      wds[c] = (unsigned)f2bf(a0) | ((unsigned)f2bf(a1) << 16);
    }
    u16* dst = h_t + ((size_t)(b * L_SEQ + l)) * C_DIM + g * 16;
    uint4 p0; p0.x = wds[0]; p0.y = wds[1]; p0.z = wds[2]; p0.w = wds[3];
    uint4 p1; p1.x = wds[4]; p1.y = wds[5]; p1.z = wds[6]; p1.w = wds[7];
    *(uint4*)dst = p0;
    *(uint4*)(dst + 8) = p1;
  }
}

// ---------------------------------------------------------------- GEMM
// MODE 0: qkv = Wqkv @ h + bias -> q_t (b,l,c) scaled; K,V in MFMA-fragment order
// MODE 1: out = Wproj @ ao + bias + x  (fp32, (b,c,l))
template <int MODE>
__global__ __launch_bounds__(256) void gemm_kernel(const u16* __restrict__ A_bf,
                                                   const u16* __restrict__ B_t,
                                                   const float* __restrict__ bias,
                                                   const float* __restrict__ xres,
                                                   u16* __restrict__ q_t,
                                                   u16* __restrict__ kf_g,
                                                   u16* __restrict__ vf_g,
                                                   float* __restrict__ out_f) {
  constexpr int K = 512;
  __shared__ u16 A_lds[128][40];
  __shared__ u16 B_lds[128][40];
  int t = threadIdx.x;
  int w = t >> 6, lane = t & 63;
  int q4 = lane >> 4, c15 = lane & 15;
  int wm = w >> 1, wn = w & 1;
  int o0 = blockIdx.y * 128;
  int l0 = blockIdx.x * 128;
  int b = blockIdx.z;
  const u16* Bb = B_t + (size_t)b * L_SEQ * K;
  f32x4 acc[4][4] = {};
  int srow = t >> 2;
  int scol = (t & 3) * 8;
  const u16* Ap = A_bf + (size_t)(o0 + srow) * K + scol;
  const u16* Bp = Bb + (size_t)(l0 + srow) * K + scol;
  for (int kt = 0; kt < K / 32; ++kt) {
    __syncthreads();
    *(uint4*)&A_lds[srow][scol] = *(const uint4*)(Ap);
    *(uint4*)&A_lds[srow + 64][scol] = *(const uint4*)(Ap + (size_t)64 * K);
    *(uint4*)&B_lds[srow][scol] = *(const uint4*)(Bp);
    *(uint4*)&B_lds[srow + 64][scol] = *(const uint4*)(Bp + (size_t)64 * K);
    Ap += 32; Bp += 32;
    __syncthreads();
    bf16x8 af[4], bfr[4];
#pragma unroll
    for (int mi = 0; mi < 4; ++mi) af[mi] = *(const bf16x8*)&A_lds[wm * 64 + mi * 16 + c15][q4 * 8];
#pragma unroll
    for (int ni = 0; ni < 4; ++ni) bfr[ni] = *(const bf16x8*)&B_lds[wn * 64 + ni * 16 + c15][q4 * 8];
#pragma unroll
    for (int mi = 0; mi < 4; ++mi)
#pragma unroll
      for (int ni = 0; ni < 4; ++ni)
        acc[mi][ni] = __builtin_amdgcn_mfma_f32_16x16x32_bf16(af[mi], bfr[ni], acc[mi][ni], 0, 0, 0);
  }

  if (MODE == 0) {
    const float QS = 0.18033688f;  // 0.125 * log2(e) folded into Q
    int sel = o0 >> 9;
    int ob = o0 - sel * 512 + wm * 64;
#pragma unroll
    for (int mi = 0; mi < 4; ++mi) {
      int orow = ob + mi * 16 + q4 * 4;
      float4 bi = *(const float4*)&bias[o0 + wm * 64 + mi * 16 + q4 * 4];
#pragma unroll
      for (int ni = 0; ni < 4; ++ni) {
        int l = l0 + wn * 64 + ni * 16 + c15;
        float v0 = acc[mi][ni][0] + bi.x;
        float v1 = acc[mi][ni][1] + bi.y;
        float v2 = acc[mi][ni][2] + bi.z;
        float v3 = acc[mi][ni][3] + bi.w;
        if (sel == 0) {
          v0 *= QS; v1 *= QS; v2 *= QS; v3 *= QS;
          uint2 pk;
          pk.x = (unsigned)f2bf(v0) | ((unsigned)f2bf(v1) << 16);
          pk.y = (unsigned)f2bf(v2) | ((unsigned)f2bf(v3) << 16);
          *(uint2*)(q_t + ((size_t)(b * L_SEQ + l)) * C_DIM + orow) = pk;
        } else if (sel == 1) {
          // K fragment: KF[bh][ (kv>>5)*4 + d>>4 ][ (kv&31)+32*hi ][ j ]
          int hh = orow >> 6, d = orow & 63;
          size_t base = ((size_t)(b * 8 + hh)) * 131072 +
                        (size_t)(((l >> 5) * 4 + (d >> 4))) * 512 +
                        (size_t)((l & 31) + ((d >> 3) & 1) * 32) * 8 + (d & 7);
          uint2 pk;
          pk.x = (unsigned)f2bf(v0) | ((unsigned)f2bf(v1) << 16);
          pk.y = (unsigned)f2bf(v2) | ((unsigned)f2bf(v3) << 16);
          *(uint2*)(kf_g + base) = pk;
        } else {
          // V fragment: VF[bh][ (kv>>4)*2 + d>>5 ][ (d&31)+32*((kv>>3)&1) ][ kv&7 ]
          int hh = orow >> 6, d = orow & 63;
          size_t base0 = ((size_t)(b * 8 + hh)) * 131072 +
                         (size_t)(l >> 4) * 1024 +
                         (size_t)((l >> 3) & 1) * 256 + (l & 7);
          vf_g[base0 + (size_t)((d + 0) >> 5) * 512 + ((d + 0) & 31) * 8] = f2bf(v0);
          vf_g[base0 + (size_t)((d + 1) >> 5) * 512 + ((d + 1) & 31) * 8] = f2bf(v1);
          vf_g[base0 + (size_t)((d + 2) >> 5) * 512 + ((d + 2) & 31) * 8] = f2bf(v2);
          vf_g[base0 + (size_t)((d + 3) >> 5) * 512 + ((d + 3) & 31) * 8] = f2bf(v3);
        }
      }
    }
  } else {
#pragma unroll
    for (int mi = 0; mi < 4; ++mi) {
      int orow = o0 + wm * 64 + mi * 16 + q4 * 4;
      float4 bi = *(const float4*)&bias[orow];
#pragma unroll
      for (int ni = 0; ni < 4; ++ni) {
        int l = l0 + wn * 64 + ni * 16 + c15;
        size_t base2 = ((size_t)(b * C_DIM + orow)) * L_SEQ + l;
        out_f[base2] = acc[mi][ni][0] + bi.x + xres[base2];
        out_f[base2 + L_SEQ] = acc[mi][ni][1] + bi.y + xres[base2 + L_SEQ];
        out_f[base2 + 2 * L_SEQ] = acc[mi][ni][2] + bi.z + xres[base2 + 2 * L_SEQ];
        out_f[base2 + 3 * L_SEQ] = acc[mi][ni][3] + bi.w + xres[base2 + 3 * L_SEQ];
      }
    }
  }
}

// ---------------------------------------------------------------- attention
// Swapped-operand flash attention; K/V pre-fragmented (coalesced loads);
// register double-buffer prefetch of next tile. No LDS, no barriers.
#define ATTN_BODY(KC, VC, KN, VN)                                              \
  {                                                                            \
    _Pragma("unroll") for (int i = 0; i < 8; ++i)                              \
        KN[i] = *(const bf16x8*)(kf + i * 512);                                \
    _Pragma("unroll") for (int i = 0; i < 8; ++i)                              \
        VN[i] = *(const bf16x8*)(vf + i * 512);                                \
    kf += 4096; vf += 4096;                                                    \
    f32x16 sa, sb;                                                             \
    _Pragma("unroll") for (int r = 0; r < 16; ++r) { sa[r] = 0.f; sb[r] = 0.f; } \
    _Pragma("unroll") for (int kk = 0; kk < 4; ++kk) {                         \
      sa = __builtin_amdgcn_mfma_f32_32x32x16_bf16(KC[kk], qf[kk], sa, 0, 0, 0); \
      sb = __builtin_amdgcn_mfma_f32_32x32x16_bf16(KC[4 + kk], qf[kk], sb, 0, 0, 0); \
    }                                                                          \
    float mt[16];                                                              \
    _Pragma("unroll") for (int r = 0; r < 16; ++r) mt[r] = fmaxf(sa[r], sb[r]); \
    _Pragma("unroll") for (int r = 0; r < 8; ++r) mt[r] = fmaxf(mt[r], mt[r + 8]); \
    _Pragma("unroll") for (int r = 0; r < 4; ++r) mt[r] = fmaxf(mt[r], mt[r + 4]); \
    float mx = fmaxf(fmaxf(mt[0], mt[1]), fmaxf(mt[2], mt[3]));                \
    mx = fmaxf(mx, __shfl_xor(mx, 32));                                        \
    if (__any(mx > m_r + 8.f)) {                                               \
      float mnew = fmaxf(m_r, mx);                                             \
      float al = __builtin_amdgcn_exp2f(m_r - mnew);                           \
      l_r *= al;                                                               \
      _Pragma("unroll") for (int r = 0; r < 16; ++r) { o0[r] *= al; o1[r] *= al; } \
      m_r = mnew;                                                              \
    }                                                                          \
    float st[16];                                                              \
    _Pragma("unroll") for (int r = 0; r < 16; ++r) {                           \
      sa[r] = __builtin_amdgcn_exp2f(sa[r] - m_r);                             \
      sb[r] = __builtin_amdgcn_exp2f(sb[r] - m_r);                             \
      st[r] = sa[r] + sb[r];                                                   \
    }                                                                          \
    _Pragma("unroll") for (int r = 0; r < 8; ++r) st[r] += st[r + 8];          \
    _Pragma("unroll") for (int r = 0; r < 4; ++r) st[r] += st[r + 4];          \
    float sum = (st[0] + st[1]) + (st[2] + st[3]);                             \
    sum += __shfl_xor(sum, 32);                                                \
    l_r += sum;                                                                \
    unsigned pka[8], pkb[8];                                                   \
    _Pragma("unroll") for (int i = 0; i < 8; ++i) {                            \
      pka[i] = cvtpk_bf16(sa[2 * i], sa[2 * i + 1]);                           \
      pkb[i] = cvtpk_bf16(sb[2 * i], sb[2 * i + 1]);                           \
    }                                                                          \
    pl32swap(pka[0], pka[2]); pl32swap(pka[1], pka[3]);                        \
    pl32swap(pka[4], pka[6]); pl32swap(pka[5], pka[7]);                        \
    pl32swap(pkb[0], pkb[2]); pl32swap(pkb[1], pkb[3]);                        \
    pl32swap(pkb[4], pkb[6]); pl32swap(pkb[5], pkb[7]);                        \
    bf16x8 pf0 = mk8(pka[0], pka[1], pka[2], pka[3]);                          \
    bf16x8 pf1 = mk8(pka[4], pka[5], pka[6], pka[7]);                          \
    bf16x8 pf2 = mk8(pkb[0], pkb[1], pkb[2], pkb[3]);                          \
    bf16x8 pf3 = mk8(pkb[4], pkb[5], pkb[6], pkb[7]);                          \
    o0 = __builtin_amdgcn_mfma_f32_32x32x16_bf16(VC[0], pf0, o0, 0, 0, 0);     \
    o1 = __builtin_amdgcn_mfma_f32_32x32x16_bf16(VC[1], pf0, o1, 0, 0, 0);     \
    o0 = __builtin_amdgcn_mfma_f32_32x32x16_bf16(VC[2], pf1, o0, 0, 0, 0);     \
    o1 = __builtin_amdgcn_mfma_f32_32x32x16_bf16(VC[3], pf1, o1, 0, 0, 0);     \
    o0 = __builtin_amdgcn_mfma_f32_32x32x16_bf16(VC[4], pf2, o0, 0, 0, 0);     \
    o1 = __builtin_amdgcn_mfma_f32_32x32x16_bf16(VC[5], pf2, o1, 0, 0, 0);     \
    o0 = __builtin_amdgcn_mfma_f32_32x32x16_bf16(VC[6], pf3, o0, 0, 0, 0);     \
    o1 = __builtin_amdgcn_mfma_f32_32x32x16_bf16(VC[7], pf3, o1, 0, 0, 0);     \
  }

__global__ __launch_bounds__(256, 2) void attn_kernel(const u16* __restrict__ q_t,
                                                      const u16* __restrict__ kf_g,
                                                      const u16* __restrict__ vf_g,
                                                      u16* __restrict__ ao_t) {
  int g = blockIdx.x;
  int wk = (g & 7) * 64 + (g >> 3);  // XCD swizzle
  int qb = wk & 15, bh = wk >> 4;
  int b = bh >> 3, h = bh & 7;
  int t = threadIdx.x;
  int wv = t >> 6, lane = t & 63;
  int q = lane & 31, hi = lane >> 5;
  int q0 = qb * 128 + wv * 32;

  const u16* qp = q_t + ((size_t)(b * L_SEQ + q0 + q)) * C_DIM + h * 64 + hi * 8;
  bf16x8 qf[4];
#pragma unroll
  for (int kk = 0; kk < 4; ++kk) qf[kk] = *(const bf16x8*)(qp + kk * 16);

  const u16* kf = kf_g + (size_t)bh * 131072 + lane * 8;
  const u16* vf = vf_g + (size_t)bh * 131072 + lane * 8;

  f32x16 o0, o1;
#pragma unroll
  for (int r = 0; r < 16; ++r) { o0[r] = 0.f; o1[r] = 0.f; }
  float m_r = -1e30f, l_r = 0.f;

  bf16x8 ka[8], va[8], kb_[8], vb_[8];
#pragma unroll
  for (int i = 0; i < 8; ++i) ka[i] = *(const bf16x8*)(kf + i * 512);
#pragma unroll
  for (int i = 0; i < 8; ++i) va[i] = *(const bf16x8*)(vf + i * 512);
  kf += 4096; vf += 4096;

  for (int kt = 0; kt < 32; kt += 2) {
    ATTN_BODY(ka, va, kb_, vb_);
    ATTN_BODY(kb_, vb_, ka, va);
  }

  float inv = 1.f / l_r;
  u16* dst = ao_t + ((size_t)(b * L_SEQ + q0 + q)) * C_DIM + h * 64;
#pragma unroll
  for (int tq = 0; tq < 4; ++tq) {
    uint2 w0, w1;
    w0.x = cvtpk_bf16(o0[4 * tq] * inv, o0[4 * tq + 1] * inv);
    w0.y = cvtpk_bf16(o0[4 * tq + 2] * inv, o0[4 * tq + 3] * inv);
    *(uint2*)(dst + 8 * tq + 4 * hi) = w0;
    w1.x = cvtpk_bf16(o1[4 * tq] * inv, o1[4 * tq + 1] * inv);
    w1.y = cvtpk_bf16(o1[4 * tq + 2] * inv, o1[4 * tq + 3] * inv);
    *(uint2*)(dst + 32 + 8 * tq + 4 * hi) = w1;
  }
}

// ---------------------------------------------------------------- launch
extern "C" void kernel_launch(void* const* d_in, const int* in_sizes, int n_in,
                              void* d_out, int out_size, void* d_ws, size_t ws_size,
                              hipStream_t stream) {
  const float* x = (const float*)d_in[0];
  const float* gamma = (const float*)d_in[1];
  const float* beta = (const float*)d_in[2];
  const float* w_qkv = (const float*)d_in[3];
  const float* b_qkv = (const float*)d_in[4];
  const float* w_proj = (const float*)d_in[5];
  const float* b_proj = (const float*)d_in[6];
  float* out = (float*)d_out;

  u16* wq_bf = (u16*)d_ws;                 // 786432
  u16* wp_bf = wq_bf + 786432;             // 262144
  u16* h_t = wp_bf + 262144;               // 4194304 (b,l,c)
  u16* q_t = h_t + 4194304;                // (b,l,c), pre-scaled
  u16* kf_g = q_t + 4194304;               // K fragments
  u16* vf_g = kf_g + 4194304;              // V fragments
  u16* ao_t = vf_g + 4194304;              // (b,l,c)

  cvt_weights<<<dim3(1024), dim3(256), 0, stream>>>(w_qkv, w_proj, wq_bf, wp_bf);
  groupnorm_kernel<<<dim3(128), dim3(256), 0, stream>>>(x, gamma, beta, h_t);
  gemm_kernel<0><<<dim3(16, 12, 4), dim3(256), 0, stream>>>(wq_bf, h_t, b_qkv, nullptr, q_t, kf_g, vf_g, nullptr);
  attn_kernel<<<dim3(512), dim3(256), 0, stream>>>(q_t, kf_g, vf_g, ao_t);
  gemm_kernel<1><<<dim3(16, 4, 4), dim3(256), 0, stream>>>(wp_bf, ao_t, b_proj, x, nullptr, nullptr, nullptr, out);
}

// Round 4
// 112.370 us; speedup vs baseline: 2.0961x; 1.1152x over previous
//
#include <hip/hip_runtime.h>
#include <stdint.h>

#define C_DIM 512
#define H_HEADS 8
#define D_HEAD 64
#define B_BATCH 4
#define L_SEQ 2048
#define GROUPS 32
#define EPS_GN 1e-5f

typedef unsigned short u16;
typedef __attribute__((ext_vector_type(8))) __bf16 bf16x8;
typedef __attribute__((ext_vector_type(4))) float f32x4;
typedef __attribute__((ext_vector_type(16))) float f32x16;

__device__ __forceinline__ u16 f2bf(float f) {
  unsigned u = __builtin_bit_cast(unsigned, f);
  unsigned r = u + 0x7FFFu + ((u >> 16) & 1u);
  return (u16)(r >> 16);
}

__device__ __forceinline__ unsigned cvtpk_bf16(float lo, float hi) {
  unsigned r;
  asm("v_cvt_pk_bf16_f32 %0, %1, %2" : "=v"(r) : "v"(lo), "v"(hi));
  return r;
}

__device__ __forceinline__ void pl32swap(unsigned& a, unsigned& b) {
  asm("v_permlane32_swap_b32 %0, %1" : "+v"(a), "+v"(b));
}

__device__ __forceinline__ bf16x8 mk8(unsigned a, unsigned b, unsigned c, unsigned d) {
  union { uint4 u; bf16x8 v; } z;
  z.u.x = a; z.u.y = b; z.u.z = c; z.u.w = d;
  return z.v;
}

// global -> LDS direct (16B per lane; dest = wave-uniform base + lane*16)
__device__ __forceinline__ void gl16(const void* g, void* l) {
  __builtin_amdgcn_global_load_lds((const __attribute__((address_space(1))) void*)g,
                                   (__attribute__((address_space(3))) void*)l, 16, 0, 0);
}

// ---------------------------------------------------------------- weights cvt
__global__ __launch_bounds__(256) void cvt_weights(const float* __restrict__ wq,
                                                   const float* __restrict__ wp,
                                                   u16* __restrict__ wq_bf,
                                                   u16* __restrict__ wp_bf) {
  int i = blockIdx.x * 256 + threadIdx.x;
  const int nq = 3 * C_DIM * C_DIM;
  int idx = i * 4;
  const float* src;
  u16* dst;
  if (idx < nq) { src = wq + idx; dst = wq_bf + idx; }
  else          { src = wp + (idx - nq); dst = wp_bf + (idx - nq); }
  float4 v = *(const float4*)src;
  uint2 pk;
  pk.x = (unsigned)f2bf(v.x) | ((unsigned)f2bf(v.y) << 16);
  pk.y = (unsigned)f2bf(v.z) | ((unsigned)f2bf(v.w) << 16);
  *(uint2*)dst = pk;
}

// ---------------------------------------------------------------- group norm
__global__ __launch_bounds__(256) void groupnorm_kernel(const float* __restrict__ x,
                                                        const float* __restrict__ gamma,
                                                        const float* __restrict__ beta,
                                                        u16* __restrict__ h_t) {
  int bg = blockIdx.x;
  int b = bg >> 5, g = bg & 31;
  const float* base = x + ((size_t)(b * C_DIM + g * 16)) * L_SEQ;
  int t = threadIdx.x;
  int w = t >> 6;
  float s = 0.f, sq = 0.f;
  for (int i = 0; i < 32; ++i) {
    float4 v = ((const float4*)base)[t + i * 256];
    s += v.x + v.y + v.z + v.w;
    sq += v.x * v.x + v.y * v.y + v.z * v.z + v.w * v.w;
  }
  for (int off = 32; off; off >>= 1) { s += __shfl_down(s, off); sq += __shfl_down(sq, off); }
  __shared__ float red[8];
  if ((t & 63) == 0) { red[w * 2] = s; red[w * 2 + 1] = sq; }
  __syncthreads();
  float ts = red[0] + red[2] + red[4] + red[6];
  float tq = red[1] + red[3] + red[5] + red[7];
  float mean = ts * (1.f / 32768.f);
  float var = tq * (1.f / 32768.f) - mean * mean;
  float rstd = rsqrtf(var + EPS_GN);
  float ga[16], be[16];
#pragma unroll
  for (int c = 0; c < 16; ++c) {
    float gm = gamma[g * 16 + c];
    ga[c] = gm * rstd;
    be[c] = beta[g * 16 + c] - mean * gm * rstd;
  }
  __shared__ float tile[16][260];
  for (int lc = 0; lc < 8; ++lc) {
    __syncthreads();
#pragma unroll
    for (int it = 0; it < 4; ++it) {
      int r = it * 4 + w;
      int c4 = (t & 63) * 4;
      *(float4*)&tile[r][c4] = *(const float4*)(base + (size_t)r * L_SEQ + lc * 256 + c4);
    }
    __syncthreads();
    int l = lc * 256 + t;
    unsigned wds[8];
#pragma unroll
    for (int c = 0; c < 8; ++c) {
      float a0 = tile[2 * c][t] * ga[2 * c] + be[2 * c];
      float a1 = tile[2 * c + 1][t] * ga[2 * c + 1] + be[2 * c + 1];
      wds[c] = (unsigned)f2bf(a0) | ((unsigned)f2bf(a1) << 16);
    }
    u16* dst = h_t + ((size_t)(b * L_SEQ + l)) * C_DIM + g * 16;
    uint4 p0; p0.x = wds[0]; p0.y = wds[1]; p0.z = wds[2]; p0.w = wds[3];
    uint4 p1; p1.x = wds[4]; p1.y = wds[5]; p1.z = wds[6]; p1.w = wds[7];
    *(uint4*)dst = p0;
    *(uint4*)(dst + 8) = p1;
  }
}

// ---------------------------------------------------------------- GEMM
// global_load_lds staging, unpadded LDS with rotate-swizzle (2-way conflicts).
// MODE 0: qkv = Wqkv @ h + bias -> q_t (b,l,c) scaled; K,V in MFMA-fragment order
// MODE 1: out = Wproj @ ao + bias + x  (fp32, (b,c,l))
template <int MODE>
__global__ __launch_bounds__(256) void gemm_kernel(const u16* __restrict__ A_bf,
                                                   const u16* __restrict__ B_t,
                                                   const float* __restrict__ bias,
                                                   const float* __restrict__ xres,
                                                   u16* __restrict__ q_t,
                                                   u16* __restrict__ kf_g,
                                                   u16* __restrict__ vf_g,
                                                   float* __restrict__ out_f) {
  constexpr int K = 512;
  __shared__ u16 A_lds[128][32];
  __shared__ u16 B_lds[128][32];
  int t = threadIdx.x;
  int w = t >> 6, lane = t & 63;
  int q4 = lane >> 4, c15 = lane & 15;
  int wm = w >> 1, wn = w & 1;
  int o0 = blockIdx.y * 128;
  int l0 = blockIdx.x * 128;
  int b = blockIdx.z;
  const u16* Bb = B_t + (size_t)b * L_SEQ * K;
  f32x4 acc[4][4] = {};

  // staging: wave w covers rows w*32..w*32+31 in two 16-row calls.
  // LDS dest is linear (lane i -> row +i>>2, chunk i&3); source pre-applies
  // the inverse rotate-swizzle so logical chunk c sits at phys (c+(row>>1))&3.
  int sr = lane >> 2, sc = lane & 3;
  int r0 = w * 32 + sr;
  int r1 = r0 + 16;
  int lc0 = (sc - (r0 >> 1)) & 3;
  int lc1 = (sc - (r1 >> 1)) & 3;
  const u16* Ag0 = A_bf + (size_t)(o0 + r0) * K + lc0 * 8;
  const u16* Ag1 = A_bf + (size_t)(o0 + r1) * K + lc1 * 8;
  const u16* Bg0 = Bb + (size_t)(l0 + r0) * K + lc0 * 8;
  const u16* Bg1 = Bb + (size_t)(l0 + r1) * K + lc1 * 8;
  u16* Al0 = &A_lds[w * 32][0];
  u16* Al1 = &A_lds[w * 32 + 16][0];
  u16* Bl0 = &B_lds[w * 32][0];
  u16* Bl1 = &B_lds[w * 32 + 16][0];

  for (int kt = 0; kt < K / 32; ++kt) {
    gl16(Ag0, Al0); gl16(Ag1, Al1);
    gl16(Bg0, Bl0); gl16(Bg1, Bl1);
    Ag0 += 32; Ag1 += 32; Bg0 += 32; Bg1 += 32;
    __syncthreads();
    bf16x8 af[4], bfr[4];
#pragma unroll
    for (int mi = 0; mi < 4; ++mi) {
      int ar = wm * 64 + mi * 16 + c15;
      af[mi] = *(const bf16x8*)&A_lds[ar][((q4 + (ar >> 1)) & 3) * 8];
    }
#pragma unroll
    for (int ni = 0; ni < 4; ++ni) {
      int br = wn * 64 + ni * 16 + c15;
      bfr[ni] = *(const bf16x8*)&B_lds[br][((q4 + (br >> 1)) & 3) * 8];
    }
#pragma unroll
    for (int mi = 0; mi < 4; ++mi)
#pragma unroll
      for (int ni = 0; ni < 4; ++ni)
        acc[mi][ni] = __builtin_amdgcn_mfma_f32_16x16x32_bf16(af[mi], bfr[ni], acc[mi][ni], 0, 0, 0);
    __syncthreads();
  }

  if (MODE == 0) {
    const float QS = 0.18033688f;  // 0.125 * log2(e) folded into Q
    int sel = o0 >> 9;
    int ob = o0 - sel * 512 + wm * 64;
#pragma unroll
    for (int mi = 0; mi < 4; ++mi) {
      int orow = ob + mi * 16 + q4 * 4;
      float4 bi = *(const float4*)&bias[o0 + wm * 64 + mi * 16 + q4 * 4];
#pragma unroll
      for (int ni = 0; ni < 4; ++ni) {
        int l = l0 + wn * 64 + ni * 16 + c15;
        float v0 = acc[mi][ni][0] + bi.x;
        float v1 = acc[mi][ni][1] + bi.y;
        float v2 = acc[mi][ni][2] + bi.z;
        float v3 = acc[mi][ni][3] + bi.w;
        if (sel == 0) {
          v0 *= QS; v1 *= QS; v2 *= QS; v3 *= QS;
          uint2 pk;
          pk.x = (unsigned)f2bf(v0) | ((unsigned)f2bf(v1) << 16);
          pk.y = (unsigned)f2bf(v2) | ((unsigned)f2bf(v3) << 16);
          *(uint2*)(q_t + ((size_t)(b * L_SEQ + l)) * C_DIM + orow) = pk;
        } else if (sel == 1) {
          // K fragment: KF[bh][(kv>>5)*4 + d>>4][(kv&31)+32*((d>>3)&1)][d&7]
          int hh = orow >> 6, d = orow & 63;
          size_t base = ((size_t)(b * 8 + hh)) * 131072 +
                        (size_t)(((l >> 5) * 4 + (d >> 4))) * 512 +
                        (size_t)((l & 31) + ((d >> 3) & 1) * 32) * 8 + (d & 7);
          uint2 pk;
          pk.x = (unsigned)f2bf(v0) | ((unsigned)f2bf(v1) << 16);
          pk.y = (unsigned)f2bf(v2) | ((unsigned)f2bf(v3) << 16);
          *(uint2*)(kf_g + base) = pk;
        } else {
          // V fragment: VF[bh][(kv>>4)*2 + d>>5][(d&31)+32*((kv>>3)&1)][kv&7]
          int hh = orow >> 6, d = orow & 63;
          size_t base0 = ((size_t)(b * 8 + hh)) * 131072 +
                         (size_t)(l >> 4) * 1024 +
                         (size_t)((l >> 3) & 1) * 256 + (l & 7);
          vf_g[base0 + (size_t)((d + 0) >> 5) * 512 + ((d + 0) & 31) * 8] = f2bf(v0);
          vf_g[base0 + (size_t)((d + 1) >> 5) * 512 + ((d + 1) & 31) * 8] = f2bf(v1);
          vf_g[base0 + (size_t)((d + 2) >> 5) * 512 + ((d + 2) & 31) * 8] = f2bf(v2);
          vf_g[base0 + (size_t)((d + 3) >> 5) * 512 + ((d + 3) & 31) * 8] = f2bf(v3);
        }
      }
    }
  } else {
#pragma unroll
    for (int mi = 0; mi < 4; ++mi) {
      int orow = o0 + wm * 64 + mi * 16 + q4 * 4;
      float4 bi = *(const float4*)&bias[orow];
#pragma unroll
      for (int ni = 0; ni < 4; ++ni) {
        int l = l0 + wn * 64 + ni * 16 + c15;
        size_t base2 = ((size_t)(b * C_DIM + orow)) * L_SEQ + l;
        out_f[base2] = acc[mi][ni][0] + bi.x + xres[base2];
        out_f[base2 + L_SEQ] = acc[mi][ni][1] + bi.y + xres[base2 + L_SEQ];
        out_f[base2 + 2 * L_SEQ] = acc[mi][ni][2] + bi.z + xres[base2 + 2 * L_SEQ];
        out_f[base2 + 3 * L_SEQ] = acc[mi][ni][3] + bi.w + xres[base2 + 3 * L_SEQ];
      }
    }
  }
}

// ---------------------------------------------------------------- attention
// T15 S-pipeline: QK^T(t+1) MFMA issued before softmax(t) VALU so the two
// interleave. kv-tile = 32 (tile stride 2048 elems, 4 chunks of 512).
// KL: buffer receiving K(t+2); KN: K(t+1) for QK; VC: V(t) for PV, then
// reloaded with V(t+2); SC: S(t) consumed by softmax; SN: S(t+1) produced.
#define ABODY(KL, KN, VC, SC, SN, T)                                           \
  {                                                                            \
    int tl = (T) + 2; tl = tl > 63 ? 63 : tl;                                  \
    const u16* kp = kfb + tl * 2048;                                           \
    const u16* vp = vfb + tl * 2048;                                           \
    KL[0] = *(const bf16x8*)(kp);                                              \
    KL[1] = *(const bf16x8*)(kp + 512);                                        \
    KL[2] = *(const bf16x8*)(kp + 1024);                                       \
    KL[3] = *(const bf16x8*)(kp + 1536);                                       \
    _Pragma("unroll") for (int r = 0; r < 16; ++r) SN[r] = 0.f;                \
    _Pragma("unroll") for (int kk = 0; kk < 4; ++kk)                           \
        SN = __builtin_amdgcn_mfma_f32_32x32x16_bf16(KN[kk], qf[kk], SN, 0, 0, 0); \
    float mx = fmaxf(fmaxf(SC[0], SC[1]), SC[2]);                              \
    float m1 = fmaxf(fmaxf(SC[3], SC[4]), SC[5]);                              \
    float m2 = fmaxf(fmaxf(SC[6], SC[7]), SC[8]);                              \
    float m3 = fmaxf(fmaxf(SC[9], SC[10]), SC[11]);                            \
    float m4 = fmaxf(fmaxf(SC[12], SC[13]), SC[14]);                           \
    mx = fmaxf(fmaxf(mx, SC[15]), fmaxf(m1, m2));                              \
    mx = fmaxf(mx, fmaxf(m3, m4));                                             \
    mx = fmaxf(mx, __shfl_xor(mx, 32));                                        \
    if (__any(mx > m_r + 8.f)) {                                               \
      float mnew = fmaxf(m_r, mx);                                             \
      float al = __builtin_amdgcn_exp2f(m_r - mnew);                           \
      l_r *= al;                                                               \
      _Pragma("unroll") for (int r = 0; r < 16; ++r) { o0[r] *= al; o1[r] *= al; } \
      m_r = mnew;                                                              \
    }                                                                          \
    _Pragma("unroll") for (int r = 0; r < 16; ++r)                             \
        SC[r] = __builtin_amdgcn_exp2f(SC[r] - m_r);                           \
    float s0 = (SC[0] + SC[1]) + (SC[2] + SC[3]);                              \
    float s1 = (SC[4] + SC[5]) + (SC[6] + SC[7]);                              \
    float s2 = (SC[8] + SC[9]) + (SC[10] + SC[11]);                            \
    float s3 = (SC[12] + SC[13]) + (SC[14] + SC[15]);                          \
    float sum = (s0 + s1) + (s2 + s3);                                         \
    sum += __shfl_xor(sum, 32);                                                \
    l_r += sum;                                                                \
    unsigned pk[8];                                                            \
    _Pragma("unroll") for (int i = 0; i < 8; ++i)                              \
        pk[i] = cvtpk_bf16(SC[2 * i], SC[2 * i + 1]);                          \
    pl32swap(pk[0], pk[2]); pl32swap(pk[1], pk[3]);                            \
    pl32swap(pk[4], pk[6]); pl32swap(pk[5], pk[7]);                            \
    bf16x8 pf0 = mk8(pk[0], pk[1], pk[2], pk[3]);                              \
    bf16x8 pf1 = mk8(pk[4], pk[5], pk[6], pk[7]);                              \
    o0 = __builtin_amdgcn_mfma_f32_32x32x16_bf16(VC[0], pf0, o0, 0, 0, 0);     \
    o1 = __builtin_amdgcn_mfma_f32_32x32x16_bf16(VC[1], pf0, o1, 0, 0, 0);     \
    o0 = __builtin_amdgcn_mfma_f32_32x32x16_bf16(VC[2], pf1, o0, 0, 0, 0);     \
    o1 = __builtin_amdgcn_mfma_f32_32x32x16_bf16(VC[3], pf1, o1, 0, 0, 0);     \
    VC[0] = *(const bf16x8*)(vp);                                              \
    VC[1] = *(const bf16x8*)(vp + 512);                                        \
    VC[2] = *(const bf16x8*)(vp + 1024);                                       \
    VC[3] = *(const bf16x8*)(vp + 1536);                                       \
  }

#define AEPI(VC, SC)                                                           \
  {                                                                            \
    float mx = fmaxf(fmaxf(SC[0], SC[1]), SC[2]);                              \
    float m1 = fmaxf(fmaxf(SC[3], SC[4]), SC[5]);                              \
    float m2 = fmaxf(fmaxf(SC[6], SC[7]), SC[8]);                              \
    float m3 = fmaxf(fmaxf(SC[9], SC[10]), SC[11]);                            \
    float m4 = fmaxf(fmaxf(SC[12], SC[13]), SC[14]);                           \
    mx = fmaxf(fmaxf(mx, SC[15]), fmaxf(m1, m2));                              \
    mx = fmaxf(mx, fmaxf(m3, m4));                                             \
    mx = fmaxf(mx, __shfl_xor(mx, 32));                                        \
    if (__any(mx > m_r + 8.f)) {                                               \
      float mnew = fmaxf(m_r, mx);                                             \
      float al = __builtin_amdgcn_exp2f(m_r - mnew);                           \
      l_r *= al;                                                               \
      _Pragma("unroll") for (int r = 0; r < 16; ++r) { o0[r] *= al; o1[r] *= al; } \
      m_r = mnew;                                                              \
    }                                                                          \
    _Pragma("unroll") for (int r = 0; r < 16; ++r)                             \
        SC[r] = __builtin_amdgcn_exp2f(SC[r] - m_r);                           \
    float s0 = (SC[0] + SC[1]) + (SC[2] + SC[3]);                              \
    float s1 = (SC[4] + SC[5]) + (SC[6] + SC[7]);                              \
    float s2 = (SC[8] + SC[9]) + (SC[10] + SC[11]);                            \
    float s3 = (SC[12] + SC[13]) + (SC[14] + SC[15]);                          \
    float sum = (s0 + s1) + (s2 + s3);                                         \
    sum += __shfl_xor(sum, 32);                                                \
    l_r += sum;                                                                \
    unsigned pk[8];                                                            \
    _Pragma("unroll") for (int i = 0; i < 8; ++i)                              \
        pk[i] = cvtpk_bf16(SC[2 * i], SC[2 * i + 1]);                          \
    pl32swap(pk[0], pk[2]); pl32swap(pk[1], pk[3]);                            \
    pl32swap(pk[4], pk[6]); pl32swap(pk[5], pk[7]);                            \
    bf16x8 pf0 = mk8(pk[0], pk[1], pk[2], pk[3]);                              \
    bf16x8 pf1 = mk8(pk[4], pk[5], pk[6], pk[7]);                              \
    o0 = __builtin_amdgcn_mfma_f32_32x32x16_bf16(VC[0], pf0, o0, 0, 0, 0);     \
    o1 = __builtin_amdgcn_mfma_f32_32x32x16_bf16(VC[1], pf0, o1, 0, 0, 0);     \
    o0 = __builtin_amdgcn_mfma_f32_32x32x16_bf16(VC[2], pf1, o0, 0, 0, 0);     \
    o1 = __builtin_amdgcn_mfma_f32_32x32x16_bf16(VC[3], pf1, o1, 0, 0, 0);     \
  }

__global__ __launch_bounds__(256, 2) void attn_kernel(const u16* __restrict__ q_t,
                                                      const u16* __restrict__ kf_g,
                                                      const u16* __restrict__ vf_g,
                                                      u16* __restrict__ ao_t) {
  int g = blockIdx.x;
  int wk = (g & 7) * 64 + (g >> 3);  // XCD swizzle
  int qb = wk & 15, bh = wk >> 4;
  int b = bh >> 3, h = bh & 7;
  int t = threadIdx.x;
  int wv = t >> 6, lane = t & 63;
  int q = lane & 31, hi = lane >> 5;
  int q0 = qb * 128 + wv * 32;

  const u16* qp = q_t + ((size_t)(b * L_SEQ + q0 + q)) * C_DIM + h * 64 + hi * 8;
  bf16x8 qf[4];
#pragma unroll
  for (int kk = 0; kk < 4; ++kk) qf[kk] = *(const bf16x8*)(qp + kk * 16);

  const u16* kfb = kf_g + (size_t)bh * 131072 + lane * 8;
  const u16* vfb = vf_g + (size_t)bh * 131072 + lane * 8;

  f32x16 o0, o1;
#pragma unroll
  for (int r = 0; r < 16; ++r) { o0[r] = 0.f; o1[r] = 0.f; }
  float m_r = -1e30f, l_r = 0.f;

  bf16x8 kA[4], kB[4], vA[4], vB[4];
#pragma unroll
  for (int i = 0; i < 4; ++i) {
    kB[i] = *(const bf16x8*)(kfb + i * 512);           // K(0)
    kA[i] = *(const bf16x8*)(kfb + 2048 + i * 512);    // K(1)
    vA[i] = *(const bf16x8*)(vfb + i * 512);           // V(0)
    vB[i] = *(const bf16x8*)(vfb + 2048 + i * 512);    // V(1)
  }
  f32x16 sA, sB;
#pragma unroll
  for (int r = 0; r < 16; ++r) sA[r] = 0.f;
#pragma unroll
  for (int kk = 0; kk < 4; ++kk)
    sA = __builtin_amdgcn_mfma_f32_32x32x16_bf16(kB[kk], qf[kk], sA, 0, 0, 0);  // S(0)

  for (int it = 0; it < 31; ++it) {
    ABODY(kB, kA, vA, sA, sB, 2 * it);
    ABODY(kA, kB, vB, sB, sA, 2 * it + 1);
  }
  ABODY(kB, kA, vA, sA, sB, 62);
  AEPI(vB, sB);

  float inv = 1.f / l_r;
  u16* dst = ao_t + ((size_t)(b * L_SEQ + q0 + q)) * C_DIM + h * 64;
#pragma unroll
  for (int tq = 0; tq < 4; ++tq) {
    uint2 w0, w1;
    w0.x = cvtpk_bf16(o0[4 * tq] * inv, o0[4 * tq + 1] * inv);
    w0.y = cvtpk_bf16(o0[4 * tq + 2] * inv, o0[4 * tq + 3] * inv);
    *(uint2*)(dst + 8 * tq + 4 * hi) = w0;
    w1.x = cvtpk_bf16(o1[4 * tq] * inv, o1[4 * tq + 1] * inv);
    w1.y = cvtpk_bf16(o1[4 * tq + 2] * inv, o1[4 * tq + 3] * inv);
    *(uint2*)(dst + 32 + 8 * tq + 4 * hi) = w1;
  }
}

// ---------------------------------------------------------------- launch
extern "C" void kernel_launch(void* const* d_in, const int* in_sizes, int n_in,
                              void* d_out, int out_size, void* d_ws, size_t ws_size,
                              hipStream_t stream) {
  const float* x = (const float*)d_in[0];
  const float* gamma = (const float*)d_in[1];
  const float* beta = (const float*)d_in[2];
  const float* w_qkv = (const float*)d_in[3];
  const float* b_qkv = (const float*)d_in[4];
  const float* w_proj = (const float*)d_in[5];
  const float* b_proj = (const float*)d_in[6];
  float* out = (float*)d_out;

  u16* wq_bf = (u16*)d_ws;                 // 786432
  u16* wp_bf = wq_bf + 786432;             // 262144
  u16* h_t = wp_bf + 262144;               // 4194304 (b,l,c)
  u16* q_t = h_t + 4194304;                // (b,l,c), pre-scaled
  u16* kf_g = q_t + 4194304;               // K fragments
  u16* vf_g = kf_g + 4194304;              // V fragments
  u16* ao_t = vf_g + 4194304;              // (b,l,c)

  cvt_weights<<<dim3(1024), dim3(256), 0, stream>>>(w_qkv, w_proj, wq_bf, wp_bf);
  groupnorm_kernel<<<dim3(128), dim3(256), 0, stream>>>(x, gamma, beta, h_t);
  gemm_kernel<0><<<dim3(16, 12, 4), dim3(256), 0, stream>>>(wq_bf, h_t, b_qkv, nullptr, q_t, kf_g, vf_g, nullptr);
  attn_kernel<<<dim3(512), dim3(256), 0, stream>>>(q_t, kf_g, vf_g, ao_t);
  gemm_kernel<1><<<dim3(16, 4, 4), dim3(256), 0, stream>>>(wp_bf, ao_t, b_proj, x, nullptr, nullptr, nullptr, out);
}